// Round 9
// baseline (32.402 us; speedup 1.0000x reference)
//
#include <hip/hip_runtime.h>

typedef short s16x8 __attribute__((ext_vector_type(8)));
typedef float f32x16 __attribute__((ext_vector_type(16)));

// MFMA forced into VGPRs ("v" forbids AGPR; "=&v" keeps dst disjoint).
// C operand = inline constant 0 (frees 16 VGPRs of zerov).
__device__ __forceinline__ f32x16 mfma0(s16x8 a, s16x8 b) {
    f32x16 d;
    asm volatile("v_mfma_f32_32x32x16_bf16 %0, %1, %2, 0"
                 : "=&v"(d) : "v"(a), "v"(b));
    return d;
}

#define VMIN3(d, a, b, c) \
    asm("v_min3_f32 %0, %1, %2, %3" : "=v"(d) : "v"(a), "v"(b), "v"(c))

#define FOLD16(mn, A) { \
        float u0, u1, u2, u3, u4, v0, v1; \
        VMIN3(u0, A[0],  A[1],  A[2]); \
        VMIN3(u1, A[3],  A[4],  A[5]); \
        VMIN3(u2, A[6],  A[7],  A[8]); \
        VMIN3(u3, A[9],  A[10], A[11]); \
        VMIN3(u4, A[12], A[13], A[14]); \
        VMIN3(v0, u0, u1, u2); \
        VMIN3(v1, u3, u4, A[15]); \
        VMIN3(mn, v0, v1, mn); \
    }

// bf16 round-to-nearest-even helpers
__device__ __forceinline__ unsigned short rne(float f) {
    unsigned u = __float_as_uint(f);
    return (unsigned short)((u + 0x7fffu + ((u >> 16) & 1u)) >> 16);
}
__device__ __forceinline__ float b2f(unsigned short b) {
    return __uint_as_float(((unsigned)b) << 16);
}

// 16-slot hi/lo-split encoding (validated rounds 4-8, absmax 0):
//   d2 = |q|^2 + |t|^2 - 2 (qh+ql).(th+tl)
__device__ __forceinline__ void encDf(float x, float y, float z, s16x8& lo, s16x8& hi) {
    const unsigned short hx = rne(x), hy = rne(y), hz = rne(z);
    const float fx = b2f(hx), fy = b2f(hy), fz = b2f(hz);
    const unsigned short lx = rne(x - fx), ly = rne(y - fy), lz = rne(z - fz);
    const float n = fmaf(x, x, fmaf(y, y, z * z));
    const unsigned short nh = rne(n), nl = rne(n - b2f(nh));
    const unsigned short m2hx = rne(-2.f * fx), m2hy = rne(-2.f * fy), m2hz = rne(-2.f * fz);
    const unsigned short m2lx = rne(-2.f * b2f(lx)), m2ly = rne(-2.f * b2f(ly)), m2lz = rne(-2.f * b2f(lz));
    lo[0]=(short)m2hx; lo[1]=(short)m2hy; lo[2]=(short)m2hz; lo[3]=(short)m2hx;
    lo[4]=(short)m2hy; lo[5]=(short)m2hz; lo[6]=(short)m2lx; lo[7]=(short)m2ly;
    hi[0]=(short)m2lz; hi[1]=(short)0x3f80; hi[2]=(short)0x3f80; hi[3]=(short)nh;
    hi[4]=(short)nl;   hi[5]=(short)m2lx;  hi[6]=(short)m2ly;   hi[7]=(short)m2lz;
}

__device__ __forceinline__ void encQf(float x, float y, float z, s16x8& lo, s16x8& hi) {
    const unsigned short hx = rne(x), hy = rne(y), hz = rne(z);
    const float fx = b2f(hx), fy = b2f(hy), fz = b2f(hz);
    const unsigned short lx = rne(x - fx), ly = rne(y - fy), lz = rne(z - fz);
    const float n = fmaf(x, x, fmaf(y, y, z * z));
    const unsigned short nh = rne(n), nl = rne(n - b2f(nh));
    lo[0]=(short)hx; lo[1]=(short)hy; lo[2]=(short)hz; lo[3]=(short)lx;
    lo[4]=(short)ly; lo[5]=(short)lz; lo[6]=(short)hx; lo[7]=(short)hy;
    hi[0]=(short)hz; hi[1]=(short)nh; hi[2]=(short)nl; hi[3]=(short)0x3f80;
    hi[4]=(short)0x3f80; hi[5]=(short)lx; hi[6]=(short)ly; hi[7]=(short)lz;
}

// ---------------------------------------------------------------------------
// preproc: encode every point ONCE to global (round-5's fusion made encD 32x
// redundant inside minpass -- the invariant ~25us cost across 3 schedules).
// D layout: byte ((b*16+split)<<14) + (tile<<10) + (half<<9) + (pt<<4)
//   -> each 512-point chunk is a contiguous 16 KiB block, linear-stageable.
// Q layout: byte ((b*256+tile)<<10) + (half<<9) + (pt<<4)
//   -> per tile, lane*16 reads lane's fragment (lane>>5 = half). 
// Also zeroes acc/ticket for the downstream reduce (stream-ordered).
// ---------------------------------------------------------------------------
__global__ void __launch_bounds__(256) preproc(
    const float* __restrict__ pred, const float* __restrict__ tgt,
    char* __restrict__ encQp, char* __restrict__ encQt,
    char* __restrict__ encDp, char* __restrict__ encDt,
    unsigned long long* __restrict__ acc, unsigned* __restrict__ ticket)
{
    const int pid = blockIdx.x * 256 + threadIdx.x;     // [0, 65536)
    if (pid == 0) { *acc = 0ull; *ticket = 0u; }
    const int which = pid >> 15, p = pid & 32767;
    const float* __restrict__ src = which ? tgt : pred;
    char* __restrict__ eQ = which ? encQt : encQp;
    char* __restrict__ eD = which ? encDt : encDp;

    const float x = src[p * 3], y = src[p * 3 + 1], z = src[p * 3 + 2];
    const int b = p >> 13, i = p & 8191;

    s16x8 qlo, qhi, dlo, dhi;
    encQf(x, y, z, qlo, qhi);
    encDf(x, y, z, dlo, dhi);

    {   // db-role
        const int split = i >> 9, idx = i & 511, tile = idx >> 5, pt = idx & 31;
        char* base = eD + (((size_t)(b * 16 + split)) << 14) + (tile << 10) + (pt << 4);
        *(s16x8*)base = dlo;
        *(s16x8*)(base + 512) = dhi;
    }
    {   // query-role
        const int tile = i >> 5, pt = i & 31;
        char* base = eQ + (((size_t)(b * 256 + tile)) << 10) + (pt << 4);
        *(s16x8*)base = qlo;
        *(s16x8*)(base + 512) = qhi;
    }
}

// ---------------------------------------------------------------------------
// minpass: bid fields qg(32) | split(16) | b(4) | pass(2).
// Prologue is now ~20 instr: linear 16 KiB chunk copy (4 int4/thread) + two
// 16B query-frag loads. Main loop: 2-stage register pipeline (round 8,
// validated): fold tiles {t,t+1} (issued one iter ago), issue {t+2,t+3}
// (ds_read one iter ago), prefetch ds_reads {t+4,t+5}.
// ---------------------------------------------------------------------------
__global__ void __launch_bounds__(256) minpass(
    const char* __restrict__ encQp, const char* __restrict__ encQt,
    const char* __restrict__ encDp, const char* __restrict__ encDt,
    float* __restrict__ part)
{
    __shared__ s16x8 sdb[16 * 64];   // [tile][half*32+pt], 16 KiB

    const int bid = blockIdx.x;
    const int qg = bid & 31, split = (bid >> 5) & 15, b = (bid >> 9) & 3, pass = bid >> 11;
    const char* __restrict__ eQ = pass ? encQt : encQp;
    const char* __restrict__ eD = pass ? encDp : encDt;

    const int tid = threadIdx.x, lane = tid & 63, wid = tid >> 6;

    // stage pre-encoded db chunk: pure linear 16 KiB copy
    {
        const int4* __restrict__ gs = (const int4*)(eD + (((size_t)(b * 16 + split)) << 14));
        int4* ld = (int4*)sdb;
        int4 r0 = gs[tid], r1 = gs[tid + 256], r2 = gs[tid + 512], r3 = gs[tid + 768];
        ld[tid] = r0; ld[tid + 256] = r1; ld[tid + 512] = r2; ld[tid + 768] = r3;
    }

    // query fragments: 2 tiles per wave, one 16B load each
    const int tq = qg * 8 + wid * 2;
    const s16x8* __restrict__ qa = (const s16x8*)(eQ + (((size_t)(b * 256 + tq)) << 10));
    const s16x8 aq0 = qa[lane];
    const s16x8 aq1 = qa[64 + lane];

    float mn0 = 3.4e38f, mn1 = 3.4e38f;

    __syncthreads();

    // prologue: tiles 0,1 issued; tiles 2,3 loaded
    s16x8 dA = sdb[lane];
    s16x8 dB = sdb[64 + lane];
    f32x16 A0 = mfma0(dA, aq0);
    f32x16 A1 = mfma0(dA, aq1);
    f32x16 B0 = mfma0(dB, aq0);
    f32x16 B1 = mfma0(dB, aq1);
    dA = sdb[2 * 64 + lane];
    dB = sdb[3 * 64 + lane];
    asm volatile("s_nop 7");

#pragma unroll
    for (int t = 0; t < 16; t += 2) {
        __builtin_amdgcn_sched_barrier(0);
        // phase A: prefetch t+4, fold tile t, issue tile t+2
        s16x8 dnA = dA;
        if (t + 4 < 16) dnA = sdb[(t + 4) * 64 + lane];
        FOLD16(mn0, A0);
        FOLD16(mn1, A1);
        if (t + 2 < 16) {
            A0 = mfma0(dA, aq0);
            A1 = mfma0(dA, aq1);
        }
        dA = dnA;
        __builtin_amdgcn_sched_barrier(0);
        // phase B: prefetch t+5, fold tile t+1, issue tile t+3
        s16x8 dnB = dB;
        if (t + 5 < 16) dnB = sdb[(t + 5) * 64 + lane];
        FOLD16(mn0, B0);
        FOLD16(mn1, B1);
        if (t + 3 < 16) {
            B0 = mfma0(dB, aq0);
            B1 = mfma0(dB, aq1);
        }
        dB = dnB;
    }
    __builtin_amdgcn_sched_barrier(0);

    mn0 = fmaxf(fminf(mn0, __shfl_xor(mn0, 32)), 0.0f);
    mn1 = fmaxf(fminf(mn1, __shfl_xor(mn1, 32)), 0.0f);

    if (lane < 32) {
        const size_t qi = ((size_t)pass << 15) + ((size_t)b << 13) + (size_t)tq * 32 + lane;
        part[(size_t)split * 65536 + qi]      = mn0;
        part[(size_t)split * 65536 + qi + 32] = mn1;
    }
}

// ---------------------------------------------------------------------------
// reduce + writeout: fold 16 split-partials per query (coalesced), sqrt, sum
// via fixed-point u64 (order-independent -> deterministic); last-ticket block
// writes the scalar.
// ---------------------------------------------------------------------------
#define FIXSCALE 1099511627776.0   // 2^40
#define RBLOCKS 128

__global__ void __launch_bounds__(256) reduce_writeout(
    const float* __restrict__ part, unsigned long long* __restrict__ acc,
    unsigned* __restrict__ ticket, float* __restrict__ out)
{
    const int q0 = blockIdx.x * 512 + threadIdx.x;
    float s = 0.0f;
#pragma unroll
    for (int k = 0; k < 2; ++k) {
        const int qi = q0 + k * 256;
        float v = part[qi];
#pragma unroll
        for (int sp = 1; sp < 16; ++sp) v = fminf(v, part[(size_t)sp * 65536 + qi]);
        s += sqrtf(v);
    }
    for (int off = 32; off; off >>= 1) s += __shfl_down(s, off, 64);
    __shared__ float ws[4];
    if ((threadIdx.x & 63) == 0) ws[threadIdx.x >> 6] = s;
    __syncthreads();
    if (threadIdx.x == 0) {
        const double t = (double)(ws[0] + ws[1] + ws[2] + ws[3]) * (1.0 / 32768.0);
        atomicAdd(acc, (unsigned long long)(t * FIXSCALE));
        __threadfence();
        const unsigned tk = atomicAdd(ticket, 1u);
        if (tk == RBLOCKS - 1) {
            const unsigned long long v = atomicAdd(acc, 0ull);
            out[0] = (float)((double)v * (1.0 / FIXSCALE));
        }
    }
}

// ---------------------------------------------------------------------------
extern "C" void kernel_launch(void* const* d_in, const int* in_sizes, int n_in,
                              void* d_out, int out_size, void* d_ws, size_t ws_size,
                              hipStream_t stream) {
    const float* pred   = (const float*)d_in[0];   // [4,8192,3]
    const float* target = (const float*)d_in[1];   // [4,8192,3]
    float* out = (float*)d_out;

    char* encQp = (char*)d_ws;                       // 1 MiB each (32768 x 32B)
    char* encQt = encQp + (1u << 20);
    char* encDp = encQp + (2u << 20);
    char* encDt = encQp + (3u << 20);
    float* part = (float*)(encQp + (4u << 20));      // [16][65536] = 4 MiB
    unsigned long long* acc = (unsigned long long*)(encQp + (8u << 20));
    unsigned* ticket = (unsigned*)(acc + 1);

    preproc<<<256, 256, 0, stream>>>(pred, target, encQp, encQt, encDp, encDt, acc, ticket);

    minpass<<<4096, 256, 0, stream>>>(encQp, encQt, encDp, encDt, part);

    reduce_writeout<<<RBLOCKS, 256, 0, stream>>>(part, acc, ticket, out);
}